// Round 3
// baseline (784.575 us; speedup 1.0000x reference)
//
#include <hip/hip_runtime.h>

// SIGN convolution: h = x @ W + b ; out = segment_sum(adj_vals[:,None] * h[edge_cols], edge_rows)
// Round 3: full row-sort -> coarse 128-row bucket sort (write-amp 8x -> ~1.5x),
// reduce via per-bucket 32KB LDS accumulator with ds_add_f32 (no row_ptr needed).

constexpr int KDIM = 256;   // n_in
constexpr int MOUT = 64;    // n_out
constexpr int TILE_R = 64;  // gemm rows per block
constexpr int KC = 64;      // gemm K chunk

constexpr int RPB = 128;        // rows per bucket (32KB LDS accumulator)
constexpr int RPB_SHIFT = 7;
constexpr int MAXBUCK = 1024;   // max buckets supported by LDS tables
constexpr int CHUNK = 8192;     // edges per scatter block
constexpr int COL_BITS = 20;    // col packed in low 20 bits, lrow in bits 20..26
constexpr int COL_MASK = (1 << COL_BITS) - 1;

// ---------------- Phase 1: dense GEMM h = x@W + b (fp32, VALU) ----------------
__global__ __launch_bounds__(256)
void gemm_xw_b(const float* __restrict__ x, const float* __restrict__ W,
               const float* __restrict__ bvec, float* __restrict__ h, int N) {
  __shared__ float xs[TILE_R][KC + 4];
  __shared__ float ws[KC][MOUT];

  const int tid = threadIdx.x;
  const int tx = tid & 15;
  const int ty = tid >> 4;
  const int row0 = blockIdx.x * TILE_R;

  float acc[4][4];
#pragma unroll
  for (int r = 0; r < 4; ++r)
#pragma unroll
    for (int c = 0; c < 4; ++c) acc[r][c] = 0.f;

  for (int kc = 0; kc < KDIM; kc += KC) {
#pragma unroll
    for (int i = 0; i < 4; ++i) {
      int flat = tid + i * 256;
      int r = flat >> 4;
      int k4 = flat & 15;
      int grow = row0 + r;
      int grc = grow < N ? grow : N - 1;
      float4 v = *reinterpret_cast<const float4*>(&x[(size_t)grc * KDIM + kc + k4 * 4]);
      *reinterpret_cast<float4*>(&xs[r][k4 * 4]) = v;
    }
#pragma unroll
    for (int i = 0; i < 4; ++i) {
      int flat = tid + i * 256;
      int k = flat >> 4;
      int c4 = flat & 15;
      float4 v = *reinterpret_cast<const float4*>(&W[(size_t)(kc + k) * MOUT + c4 * 4]);
      *reinterpret_cast<float4*>(&ws[k][c4 * 4]) = v;
    }
    __syncthreads();

#pragma unroll 16
    for (int k = 0; k < KC; ++k) {
      float a0 = xs[ty * 4 + 0][k];
      float a1 = xs[ty * 4 + 1][k];
      float a2 = xs[ty * 4 + 2][k];
      float a3 = xs[ty * 4 + 3][k];
      float4 bq = *reinterpret_cast<const float4*>(&ws[k][tx * 4]);
      acc[0][0] += a0 * bq.x; acc[0][1] += a0 * bq.y; acc[0][2] += a0 * bq.z; acc[0][3] += a0 * bq.w;
      acc[1][0] += a1 * bq.x; acc[1][1] += a1 * bq.y; acc[1][2] += a1 * bq.z; acc[1][3] += a1 * bq.w;
      acc[2][0] += a2 * bq.x; acc[2][1] += a2 * bq.y; acc[2][2] += a2 * bq.z; acc[2][3] += a2 * bq.w;
      acc[3][0] += a3 * bq.x; acc[3][1] += a3 * bq.y; acc[3][2] += a3 * bq.z; acc[3][3] += a3 * bq.w;
    }
    __syncthreads();
  }

  float4 bb = *reinterpret_cast<const float4*>(&bvec[tx * 4]);
#pragma unroll
  for (int r = 0; r < 4; ++r) {
    int grow = row0 + ty * 4 + r;
    if (grow < N) {
      float4 o;
      o.x = acc[r][0] + bb.x;
      o.y = acc[r][1] + bb.y;
      o.z = acc[r][2] + bb.z;
      o.w = acc[r][3] + bb.w;
      *reinterpret_cast<float4*>(&h[(size_t)grow * MOUT + tx * 4]) = o;
    }
  }
}

// ---------------- Bucket CSR build ----------------
// Histogram of edges per 128-row bucket; LDS-aggregated, one global add per (block,bucket).
__global__ __launch_bounds__(256)
void bucket_hist(const int* __restrict__ rows, int* __restrict__ bcnt, int E, int nbuck) {
  __shared__ int cnt[MAXBUCK];
  for (int i = threadIdx.x; i < nbuck; i += 256) cnt[i] = 0;
  __syncthreads();
  for (int e = blockIdx.x * 256 + threadIdx.x; e < E; e += gridDim.x * 256)
    atomicAdd(&cnt[rows[e] >> RPB_SHIFT], 1);
  __syncthreads();
  for (int i = threadIdx.x; i < nbuck; i += 256)
    if (cnt[i]) atomicAdd(&bcnt[i], cnt[i]);
}

// Single-block exclusive scan of bucket counts (nbuck <= 1024).
__global__ __launch_bounds__(1024)
void scan_buckets(const int* __restrict__ bcnt, int* __restrict__ bptr,
                  int* __restrict__ bcur, int nbuck, int E) {
  __shared__ int buf[1024];
  int t = threadIdx.x;
  int x = (t < nbuck) ? bcnt[t] : 0;
  buf[t] = x;
  __syncthreads();
#pragma unroll
  for (int off = 1; off < 1024; off <<= 1) {
    int v = (t >= off) ? buf[t - off] : 0;
    __syncthreads();
    buf[t] += v;
    __syncthreads();
  }
  if (t < nbuck) {
    int ex = buf[t] - x;
    bptr[t] = ex;
    bcur[t] = ex;
  }
  if (t == 0) bptr[nbuck] = E;
}

// Scatter edges into bucket-grouped order. Per block: LDS histogram of its CHUNK,
// one global atomicAdd per non-empty bucket to reserve a contiguous range, then
// place edges via LDS cursors. Payload: (lrow<<20 | col, val_bits).
__global__ __launch_bounds__(256)
void bucket_scatter(const int* __restrict__ rows, const int* __restrict__ cols,
                    const float* __restrict__ vals, int* __restrict__ bcur,
                    int2* __restrict__ sorted, int E, int nbuck) {
  __shared__ int lcnt[MAXBUCK];
  __shared__ int lbase[MAXBUCK];
  const int t = threadIdx.x;
  const int e0 = blockIdx.x * CHUNK;
  const int e1 = min(e0 + CHUNK, E);

  for (int i = t; i < nbuck; i += 256) lcnt[i] = 0;
  __syncthreads();
  for (int e = e0 + t; e < e1; e += 256)
    atomicAdd(&lcnt[rows[e] >> RPB_SHIFT], 1);
  __syncthreads();
  for (int i = t; i < nbuck; i += 256) {
    int c = lcnt[i];
    lbase[i] = c ? atomicAdd(&bcur[i], c) : 0;
  }
  __syncthreads();
  for (int i = t; i < nbuck; i += 256) lcnt[i] = 0;
  __syncthreads();
  for (int e = e0 + t; e < e1; e += 256) {
    int r = rows[e];
    int b = r >> RPB_SHIFT;
    int lrow = r & (RPB - 1);
    int pos = lbase[b] + atomicAdd(&lcnt[b], 1);
    sorted[pos] = make_int2((lrow << COL_BITS) | cols[e], __float_as_int(vals[e]));
  }
}

// ---------------- Reduce: one block per bucket, 32KB LDS accumulator ----------------
// 256 threads = 16 edge-slots x 16 parts (float4 of the 64-wide row).
__global__ __launch_bounds__(256)
void bucket_reduce(const float* __restrict__ h, const int2* __restrict__ sorted,
                   const int* __restrict__ bptr, float* __restrict__ out, int N) {
  __shared__ __align__(16) float acc[RPB * MOUT];  // 32 KB
  const int t = threadIdx.x;
  const int blk = blockIdx.x;
  for (int i = t; i < RPB * MOUT; i += 256) acc[i] = 0.f;
  __syncthreads();

  const int slot = t >> 4;
  const int part = t & 15;
  const int s = bptr[blk];
  const int e = bptr[blk + 1];
  for (int j = s + slot; j < e; j += 16) {
    int2 p = sorted[j];
    float v = __int_as_float(p.y);
    int col = p.x & COL_MASK;
    int lrow = p.x >> COL_BITS;
    float4 hv = *reinterpret_cast<const float4*>(&h[(size_t)col * MOUT + part * 4]);
    float* a = &acc[lrow * MOUT + part * 4];
    atomicAdd(a + 0, v * hv.x);
    atomicAdd(a + 1, v * hv.y);
    atomicAdd(a + 2, v * hv.z);
    atomicAdd(a + 3, v * hv.w);
  }
  __syncthreads();

  const int row0 = blk * RPB;
  for (int i = t; i < RPB * (MOUT / 4); i += 256) {  // 2048 float4 stores
    int lr = i >> 4;
    int c4 = i & 15;
    int grow = row0 + lr;
    if (grow < N)
      *reinterpret_cast<float4*>(&out[(size_t)grow * MOUT + c4 * 4]) =
          *reinterpret_cast<const float4*>(&acc[lr * MOUT + c4 * 4]);
  }
}

// ---------------- Fallback: f32-atomic scatter (ws too small / N too big) ----------------
__global__ __launch_bounds__(256)
void scatter_edges(const float* __restrict__ h, const float* __restrict__ vals,
                   const int* __restrict__ rows, const int* __restrict__ cols,
                   float* __restrict__ out, int E) {
  long long idx = (long long)blockIdx.x * blockDim.x + threadIdx.x;
  int e = (int)(idx >> 4);
  int part = (int)(idx & 15);
  if (e >= E) return;
  int r = rows[e];
  int c = cols[e];
  float v = vals[e];
  float4 hv = *reinterpret_cast<const float4*>(&h[(size_t)c * MOUT + part * 4]);
  float* op = &out[(size_t)r * MOUT + part * 4];
  atomicAdd(op + 0, v * hv.x);
  atomicAdd(op + 1, v * hv.y);
  atomicAdd(op + 2, v * hv.z);
  atomicAdd(op + 3, v * hv.w);
}

static inline size_t align256(size_t x) { return (x + 255) & ~(size_t)255; }

extern "C" void kernel_launch(void* const* d_in, const int* in_sizes, int n_in,
                              void* d_out, int out_size, void* d_ws, size_t ws_size,
                              hipStream_t stream) {
  const float* x    = (const float*)d_in[0];
  const float* W    = (const float*)d_in[1];
  const float* bvec = (const float*)d_in[2];
  const float* vals = (const float*)d_in[3];
  const int* erows  = (const int*)d_in[4];
  const int* ecols  = (const int*)d_in[5];
  float* out = (float*)d_out;

  const int N = in_sizes[0] / KDIM;   // 100000
  const int E = in_sizes[3];          // 1600000
  const int nbuck = (N + RPB - 1) / RPB;  // 782

  // workspace layout
  char* ws = (char*)d_ws;
  size_t off_h  = 0;
  size_t off_bp = align256(off_h + (size_t)N * MOUT * sizeof(float));
  size_t off_bc = align256(off_bp + (size_t)(nbuck + 1) * sizeof(int));
  size_t off_cu = align256(off_bc + (size_t)nbuck * sizeof(int));
  size_t off_sp = align256(off_cu + (size_t)nbuck * sizeof(int));
  size_t need   = off_sp + (size_t)E * sizeof(int2);

  float* h = (float*)(ws + off_h);

  dim3 blk256(256);
  gemm_xw_b<<<dim3((N + TILE_R - 1) / TILE_R), blk256, 0, stream>>>(x, W, bvec, h, N);

  if (ws_size >= need && nbuck <= MAXBUCK && N < (1 << COL_BITS)) {
    int* bptr = (int*)(ws + off_bp);
    int* bcnt = (int*)(ws + off_bc);
    int* bcur = (int*)(ws + off_cu);
    int2* sorted = (int2*)(ws + off_sp);

    hipMemsetAsync(bcnt, 0, (size_t)nbuck * sizeof(int), stream);
    bucket_hist<<<dim3(256), blk256, 0, stream>>>(erows, bcnt, E, nbuck);
    scan_buckets<<<dim3(1), dim3(1024), 0, stream>>>(bcnt, bptr, bcur, nbuck, E);
    bucket_scatter<<<dim3((E + CHUNK - 1) / CHUNK), blk256, 0, stream>>>(
        erows, ecols, vals, bcur, sorted, E, nbuck);
    bucket_reduce<<<dim3(nbuck), blk256, 0, stream>>>(h, sorted, bptr, out, N);
  } else {
    hipMemsetAsync(d_out, 0, (size_t)out_size * sizeof(float), stream);
    long long work = (long long)E * 16;
    scatter_edges<<<dim3((unsigned)((work + 255) / 256)), blk256, 0, stream>>>(h, vals, erows, ecols, out, E);
  }
}

// Round 4
// 196.704 us; speedup vs baseline: 3.9886x; 3.9886x over previous
//
#include <hip/hip_runtime.h>

// SIGN convolution: h = x @ W + b ; out = segment_sum(adj_vals[:,None] * h[edge_cols], edge_rows)
// Round 4: bucket scatter (low write-amp, from r3) + in-LDS per-bucket counting sort
// (full row order + row_ptr) + round-2's high-occupancy one-wave-per-row reduce.
// r3 post-mortem: one-block-per-bucket reduce was latency-bound at 20% occupancy (680us).

constexpr int KDIM = 256;   // n_in
constexpr int MOUT = 64;    // n_out
constexpr int TILE_R = 64;  // gemm rows per block
constexpr int KC = 64;      // gemm K chunk

constexpr int RPB = 128;        // rows per bucket
constexpr int RPB_SHIFT = 7;
constexpr int MAXBUCK = 1024;   // max buckets (LDS tables in hist/scatter)
constexpr int CHUNK = 8192;     // edges per scatter block
constexpr int COL_BITS = 20;    // col in low 20 bits, lrow in bits 20..26
constexpr int COL_MASK = (1 << COL_BITS) - 1;
constexpr int SORT_CAP = 6144;  // max edges staged per bucket (48KB LDS); mean=2046 here

// ---------------- Phase 1: dense GEMM h = x@W + b (fp32, VALU) ----------------
__global__ __launch_bounds__(256)
void gemm_xw_b(const float* __restrict__ x, const float* __restrict__ W,
               const float* __restrict__ bvec, float* __restrict__ h, int N) {
  __shared__ float xs[TILE_R][KC + 4];
  __shared__ float ws[KC][MOUT];

  const int tid = threadIdx.x;
  const int tx = tid & 15;
  const int ty = tid >> 4;
  const int row0 = blockIdx.x * TILE_R;

  float acc[4][4];
#pragma unroll
  for (int r = 0; r < 4; ++r)
#pragma unroll
    for (int c = 0; c < 4; ++c) acc[r][c] = 0.f;

  for (int kc = 0; kc < KDIM; kc += KC) {
#pragma unroll
    for (int i = 0; i < 4; ++i) {
      int flat = tid + i * 256;
      int r = flat >> 4;
      int k4 = flat & 15;
      int grow = row0 + r;
      int grc = grow < N ? grow : N - 1;
      float4 v = *reinterpret_cast<const float4*>(&x[(size_t)grc * KDIM + kc + k4 * 4]);
      *reinterpret_cast<float4*>(&xs[r][k4 * 4]) = v;
    }
#pragma unroll
    for (int i = 0; i < 4; ++i) {
      int flat = tid + i * 256;
      int k = flat >> 4;
      int c4 = flat & 15;
      float4 v = *reinterpret_cast<const float4*>(&W[(size_t)(kc + k) * MOUT + c4 * 4]);
      *reinterpret_cast<float4*>(&ws[k][c4 * 4]) = v;
    }
    __syncthreads();

#pragma unroll 16
    for (int k = 0; k < KC; ++k) {
      float a0 = xs[ty * 4 + 0][k];
      float a1 = xs[ty * 4 + 1][k];
      float a2 = xs[ty * 4 + 2][k];
      float a3 = xs[ty * 4 + 3][k];
      float4 bq = *reinterpret_cast<const float4*>(&ws[k][tx * 4]);
      acc[0][0] += a0 * bq.x; acc[0][1] += a0 * bq.y; acc[0][2] += a0 * bq.z; acc[0][3] += a0 * bq.w;
      acc[1][0] += a1 * bq.x; acc[1][1] += a1 * bq.y; acc[1][2] += a1 * bq.z; acc[1][3] += a1 * bq.w;
      acc[2][0] += a2 * bq.x; acc[2][1] += a2 * bq.y; acc[2][2] += a2 * bq.z; acc[2][3] += a2 * bq.w;
      acc[3][0] += a3 * bq.x; acc[3][1] += a3 * bq.y; acc[3][2] += a3 * bq.z; acc[3][3] += a3 * bq.w;
    }
    __syncthreads();
  }

  float4 bb = *reinterpret_cast<const float4*>(&bvec[tx * 4]);
#pragma unroll
  for (int r = 0; r < 4; ++r) {
    int grow = row0 + ty * 4 + r;
    if (grow < N) {
      float4 o;
      o.x = acc[r][0] + bb.x;
      o.y = acc[r][1] + bb.y;
      o.z = acc[r][2] + bb.z;
      o.w = acc[r][3] + bb.w;
      *reinterpret_cast<float4*>(&h[(size_t)grow * MOUT + tx * 4]) = o;
    }
  }
}

// ---------------- Bucket CSR build ----------------
__global__ __launch_bounds__(256)
void bucket_hist(const int* __restrict__ rows, int* __restrict__ bcnt, int E, int nbuck) {
  __shared__ int cnt[MAXBUCK];
  for (int i = threadIdx.x; i < nbuck; i += 256) cnt[i] = 0;
  __syncthreads();
  for (int e = blockIdx.x * 256 + threadIdx.x; e < E; e += gridDim.x * 256)
    atomicAdd(&cnt[rows[e] >> RPB_SHIFT], 1);
  __syncthreads();
  for (int i = threadIdx.x; i < nbuck; i += 256)
    if (cnt[i]) atomicAdd(&bcnt[i], cnt[i]);
}

__global__ __launch_bounds__(1024)
void scan_buckets(const int* __restrict__ bcnt, int* __restrict__ bptr,
                  int* __restrict__ bcur, int nbuck, int E) {
  __shared__ int buf[1024];
  int t = threadIdx.x;
  int x = (t < nbuck) ? bcnt[t] : 0;
  buf[t] = x;
  __syncthreads();
#pragma unroll
  for (int off = 1; off < 1024; off <<= 1) {
    int v = (t >= off) ? buf[t - off] : 0;
    __syncthreads();
    buf[t] += v;
    __syncthreads();
  }
  if (t < nbuck) {
    int ex = buf[t] - x;
    bptr[t] = ex;
    bcur[t] = ex;
  }
  if (t == 0) bptr[nbuck] = E;
}

// Scatter edges into bucket-grouped order; per-block LDS hist + one range-reserve
// atomic per (block,bucket). Payload: (lrow<<20 | col, val_bits).
__global__ __launch_bounds__(256)
void bucket_scatter(const int* __restrict__ rows, const int* __restrict__ cols,
                    const float* __restrict__ vals, int* __restrict__ bcur,
                    int2* __restrict__ sorted, int E, int nbuck) {
  __shared__ int lcnt[MAXBUCK];
  __shared__ int lbase[MAXBUCK];
  const int t = threadIdx.x;
  const int e0 = blockIdx.x * CHUNK;
  const int e1 = min(e0 + CHUNK, E);

  for (int i = t; i < nbuck; i += 256) lcnt[i] = 0;
  __syncthreads();
  for (int e = e0 + t; e < e1; e += 256)
    atomicAdd(&lcnt[rows[e] >> RPB_SHIFT], 1);
  __syncthreads();
  for (int i = t; i < nbuck; i += 256) {
    int c = lcnt[i];
    lbase[i] = c ? atomicAdd(&bcur[i], c) : 0;
  }
  __syncthreads();
  for (int i = t; i < nbuck; i += 256) lcnt[i] = 0;
  __syncthreads();
  for (int e = e0 + t; e < e1; e += 256) {
    int r = rows[e];
    int b = r >> RPB_SHIFT;
    int lrow = r & (RPB - 1);
    int pos = lbase[b] + atomicAdd(&lcnt[b], 1);
    sorted[pos] = make_int2((lrow << COL_BITS) | cols[e], __float_as_int(vals[e]));
  }
}

// Per-bucket in-LDS counting sort by lrow (in place) + row_ptr emission.
// Overflow buckets (> SORT_CAP edges) are left unsorted with bflag set; the
// reduce then filter-scans the whole bucket for those rows (correctness fallback).
__global__ __launch_bounds__(256)
void bucket_sort(int2* __restrict__ sorted, const int* __restrict__ bptr,
                 int* __restrict__ row_ptr, int* __restrict__ bflag,
                 int N, int E, int nbuck) {
  __shared__ int2 eds[SORT_CAP];   // 48 KB
  __shared__ int lcnt[RPB];
  __shared__ int loff[RPB];
  __shared__ int lcur[RPB];
  const int t = threadIdx.x;
  const int b = blockIdx.x;
  const int s = bptr[b];
  const int e = bptr[b + 1];
  const int cnt = e - s;
  const int row0 = b << RPB_SHIFT;

  if (b == 0 && t == 0) row_ptr[N] = E;

  if (cnt > SORT_CAP) {  // correctness fallback (never for uniform data)
    if (t == 0) bflag[b] = 1;
    if (t < RPB && row0 + t < N) row_ptr[row0 + t] = s;
    return;
  }
  if (t == 0) bflag[b] = 0;

  if (t < RPB) lcnt[t] = 0;
  __syncthreads();
  for (int j = s + t; j < e; j += 256) {
    int2 p = sorted[j];
    eds[j - s] = p;
    atomicAdd(&lcnt[p.x >> COL_BITS], 1);
  }
  __syncthreads();
  // exclusive scan of lcnt[0..127]
  if (t < RPB) loff[t] = lcnt[t];
  __syncthreads();
  for (int off = 1; off < RPB; off <<= 1) {
    int v = (t < RPB && t >= off) ? loff[t - off] : 0;
    __syncthreads();
    if (t < RPB) loff[t] += v;
    __syncthreads();
  }
  if (t < RPB) {
    int ex = loff[t] - lcnt[t];
    loff[t] = ex;
    lcur[t] = 0;
    int grow = row0 + t;
    if (grow < N) row_ptr[grow] = s + ex;
  }
  __syncthreads();
  for (int idx = t; idx < cnt; idx += 256) {
    int2 p = eds[idx];
    int lr = p.x >> COL_BITS;
    int pos = s + loff[lr] + atomicAdd(&lcur[lr], 1);
    sorted[pos] = p;
  }
}

// ---------------- Reduce: one wave per output row ----------------
// lane = sub*16 + part; 16 parts cover the 64-wide row as float4; 4 edge-slots
// in parallel; shfl_xor folds the slots. lrow bits in p.x are masked off.
__global__ __launch_bounds__(256)
void reduce_rows(const float* __restrict__ h, const int2* __restrict__ sorted,
                 const int* __restrict__ row_ptr, const int* __restrict__ bptr,
                 const int* __restrict__ bflag, float* __restrict__ out, int N) {
  int row = (blockIdx.x * 256 + threadIdx.x) >> 6;
  if (row >= N) return;
  int lane = threadIdx.x & 63;
  int sub = lane >> 4;
  int part = lane & 15;
  int b = row >> RPB_SHIFT;
  int lrow = row & (RPB - 1);
  bool filt = bflag[b] != 0;
  int s, e;
  if (!filt) {
    s = row_ptr[row];
    e = row_ptr[row + 1];
  } else {
    s = bptr[b];
    e = bptr[b + 1];
  }
  float4 acc = make_float4(0.f, 0.f, 0.f, 0.f);
  for (int j = s + sub; j < e; j += 4) {
    int2 p = sorted[j];
    if (filt && (p.x >> COL_BITS) != lrow) continue;
    float v = __int_as_float(p.y);
    int col = p.x & COL_MASK;
    float4 hv = *reinterpret_cast<const float4*>(&h[(size_t)col * MOUT + part * 4]);
    acc.x += v * hv.x;
    acc.y += v * hv.y;
    acc.z += v * hv.z;
    acc.w += v * hv.w;
  }
#pragma unroll
  for (int m = 16; m <= 32; m <<= 1) {
    acc.x += __shfl_xor(acc.x, m, 64);
    acc.y += __shfl_xor(acc.y, m, 64);
    acc.z += __shfl_xor(acc.z, m, 64);
    acc.w += __shfl_xor(acc.w, m, 64);
  }
  if (sub == 0)
    *reinterpret_cast<float4*>(&out[(size_t)row * MOUT + part * 4]) = acc;
}

// ---------------- Fallback: f32-atomic scatter ----------------
__global__ __launch_bounds__(256)
void scatter_edges(const float* __restrict__ h, const float* __restrict__ vals,
                   const int* __restrict__ rows, const int* __restrict__ cols,
                   float* __restrict__ out, int E) {
  long long idx = (long long)blockIdx.x * blockDim.x + threadIdx.x;
  int e = (int)(idx >> 4);
  int part = (int)(idx & 15);
  if (e >= E) return;
  int r = rows[e];
  int c = cols[e];
  float v = vals[e];
  float4 hv = *reinterpret_cast<const float4*>(&h[(size_t)c * MOUT + part * 4]);
  float* op = &out[(size_t)r * MOUT + part * 4];
  atomicAdd(op + 0, v * hv.x);
  atomicAdd(op + 1, v * hv.y);
  atomicAdd(op + 2, v * hv.z);
  atomicAdd(op + 3, v * hv.w);
}

static inline size_t align256(size_t x) { return (x + 255) & ~(size_t)255; }

extern "C" void kernel_launch(void* const* d_in, const int* in_sizes, int n_in,
                              void* d_out, int out_size, void* d_ws, size_t ws_size,
                              hipStream_t stream) {
  const float* x    = (const float*)d_in[0];
  const float* W    = (const float*)d_in[1];
  const float* bvec = (const float*)d_in[2];
  const float* vals = (const float*)d_in[3];
  const int* erows  = (const int*)d_in[4];
  const int* ecols  = (const int*)d_in[5];
  float* out = (float*)d_out;

  const int N = in_sizes[0] / KDIM;   // 100000
  const int E = in_sizes[3];          // 1600000
  const int nbuck = (N + RPB - 1) / RPB;  // 782

  // workspace layout (~38.9 MB)
  char* ws = (char*)d_ws;
  size_t off_h  = 0;
  size_t off_bp = align256(off_h + (size_t)N * MOUT * sizeof(float));
  size_t off_bc = align256(off_bp + (size_t)(nbuck + 1) * sizeof(int));
  size_t off_cu = align256(off_bc + (size_t)nbuck * sizeof(int));
  size_t off_bf = align256(off_cu + (size_t)nbuck * sizeof(int));
  size_t off_rp = align256(off_bf + (size_t)nbuck * sizeof(int));
  size_t off_sp = align256(off_rp + (size_t)(N + 1) * sizeof(int));
  size_t need   = off_sp + (size_t)E * sizeof(int2);

  float* h = (float*)(ws + off_h);

  dim3 blk256(256);
  gemm_xw_b<<<dim3((N + TILE_R - 1) / TILE_R), blk256, 0, stream>>>(x, W, bvec, h, N);

  if (ws_size >= need && nbuck <= MAXBUCK && N < (1 << COL_BITS)) {
    int* bptr  = (int*)(ws + off_bp);
    int* bcnt  = (int*)(ws + off_bc);
    int* bcur  = (int*)(ws + off_cu);
    int* bflag = (int*)(ws + off_bf);
    int* row_ptr = (int*)(ws + off_rp);
    int2* sorted = (int2*)(ws + off_sp);

    hipMemsetAsync(bcnt, 0, (size_t)nbuck * sizeof(int), stream);
    bucket_hist<<<dim3(256), blk256, 0, stream>>>(erows, bcnt, E, nbuck);
    scan_buckets<<<dim3(1), dim3(1024), 0, stream>>>(bcnt, bptr, bcur, nbuck, E);
    bucket_scatter<<<dim3((E + CHUNK - 1) / CHUNK), blk256, 0, stream>>>(
        erows, ecols, vals, bcur, sorted, E, nbuck);
    bucket_sort<<<dim3(nbuck), blk256, 0, stream>>>(sorted, bptr, row_ptr, bflag, N, E, nbuck);
    reduce_rows<<<dim3(((size_t)N * 64 + 255) / 256), blk256, 0, stream>>>(
        h, sorted, row_ptr, bptr, bflag, out, N);
  } else {
    hipMemsetAsync(d_out, 0, (size_t)out_size * sizeof(float), stream);
    long long work = (long long)E * 16;
    scatter_edges<<<dim3((unsigned)((work + 255) / 256)), blk256, 0, stream>>>(h, vals, erows, ecols, out, E);
  }
}

// Round 5
// 161.969 us; speedup vs baseline: 4.8440x; 1.2145x over previous
//
#include <hip/hip_runtime.h>

// SIGN convolution: h = x @ W + b ; out = segment_sum(adj_vals[:,None] * h[edge_cols], edge_rows)
// Round 5: GEMM -> bf16 MFMA (mfma_f32_16x16x32_bf16), h stored as bf16 (halves
// GEMM writes and reduce gather traffic). CSR pipeline (r4) unchanged.
// k-permutation invariance: A and B fragments use the SAME (hi,j)->k map, so the
// result is correct under either gfx950 K-doubling convention. C/D layout per m89.

#include <stdint.h>

constexpr int KDIM = 256;   // n_in
constexpr int MOUT = 64;    // n_out

constexpr int RPB = 128;        // rows per bucket
constexpr int RPB_SHIFT = 7;
constexpr int MAXBUCK = 1024;
constexpr int CHUNK = 8192;     // edges per scatter block
constexpr int COL_BITS = 20;
constexpr int COL_MASK = (1 << COL_BITS) - 1;
constexpr int SORT_CAP = 6144;  // 48KB LDS stage; mean bucket = 2046 here

typedef __attribute__((ext_vector_type(8))) short short8v;
typedef __attribute__((ext_vector_type(4))) float f32x4;

__device__ __forceinline__ unsigned short f2bf(float f) {
  unsigned u = __float_as_uint(f);
  return (unsigned short)((u + 0x7fffu + ((u >> 16) & 1u)) >> 16);
}

// ---------------- W transpose + bf16 convert (one-time, 32KB) ----------------
// wt[n][k] bf16 bits, n=0..63, k=0..255.
__global__ __launch_bounds__(256)
void wt_transpose(const float* __restrict__ W, unsigned short* __restrict__ wt) {
  int n = blockIdx.x;
  int k = threadIdx.x;
  wt[n * KDIM + k] = f2bf(W[(size_t)k * MOUT + n]);
}

// ---------------- Phase 1: h = bf16(x @ W + b) via MFMA ----------------
// 4 waves/block; wave handles 32 rows (2 mrep x 16); block = 128 rows.
// A-frag: row = lane&15, k = ks*32 + (lane>>4)*8 + j  (from global x, cvt to bf16)
// B-frag: col = lane&15, k same map                    (from padded LDS copy of wt)
// D: row = (lane>>4)*4 + reg, col = lane&15            (verified layout)
__global__ __launch_bounds__(256)
void gemm_mfma(const float* __restrict__ x, const unsigned short* __restrict__ wt,
               const float* __restrict__ bvec, unsigned short* __restrict__ h, int N) {
  __shared__ unsigned short wlds[MOUT][264];  // 528B rows: 2-way bank aliasing only

  const int t = threadIdx.x;
  // stage wt (already [n][k] bf16) into LDS with +8-short row pad; 16B chunks
  for (int i = t; i < MOUT * 32; i += 256) {
    int n = i >> 5, seg = i & 31;
    uint4 v = *reinterpret_cast<const uint4*>(&wt[n * KDIM + seg * 8]);
    *reinterpret_cast<uint4*>(&wlds[n][seg * 8]) = v;
  }
  __syncthreads();

  const int wave = t >> 6, lane = t & 63;
  const int lo = lane & 15, hi = lane >> 4;
  const int rowbase = blockIdx.x * 128 + wave * 32;

  float bias[4];
#pragma unroll
  for (int nt = 0; nt < 4; ++nt) bias[nt] = bvec[nt * 16 + lo];

  f32x4 acc[2][4] = {};

#pragma unroll
  for (int ks = 0; ks < 8; ++ks) {
    short8v bfr[4];
#pragma unroll
    for (int nt = 0; nt < 4; ++nt)
      bfr[nt] = *reinterpret_cast<const short8v*>(&wlds[nt * 16 + lo][ks * 32 + hi * 8]);
#pragma unroll
    for (int mr = 0; mr < 2; ++mr) {
      int r = rowbase + mr * 16 + lo;
      if (r >= N) r = N - 1;  // clamp; stores guarded
      const float* xp = &x[(size_t)r * KDIM + ks * 32 + hi * 8];
      float4 p0 = *reinterpret_cast<const float4*>(xp);
      float4 p1 = *reinterpret_cast<const float4*>(xp + 4);
      short8v a;
      a[0] = (short)f2bf(p0.x); a[1] = (short)f2bf(p0.y);
      a[2] = (short)f2bf(p0.z); a[3] = (short)f2bf(p0.w);
      a[4] = (short)f2bf(p1.x); a[5] = (short)f2bf(p1.y);
      a[6] = (short)f2bf(p1.z); a[7] = (short)f2bf(p1.w);
#pragma unroll
      for (int nt = 0; nt < 4; ++nt)
        acc[mr][nt] = __builtin_amdgcn_mfma_f32_16x16x32_bf16(a, bfr[nt], acc[mr][nt], 0, 0, 0);
    }
  }

#pragma unroll
  for (int mr = 0; mr < 2; ++mr)
#pragma unroll
    for (int reg = 0; reg < 4; ++reg) {
      int row = rowbase + mr * 16 + hi * 4 + reg;
      if (row < N) {
#pragma unroll
        for (int nt = 0; nt < 4; ++nt)
          h[(size_t)row * MOUT + nt * 16 + lo] = f2bf(acc[mr][nt][reg] + bias[nt]);
      }
    }
}

// ---------------- Bucket CSR build (unchanged from r4) ----------------
__global__ __launch_bounds__(256)
void bucket_hist(const int* __restrict__ rows, int* __restrict__ bcnt, int E, int nbuck) {
  __shared__ int cnt[MAXBUCK];
  for (int i = threadIdx.x; i < nbuck; i += 256) cnt[i] = 0;
  __syncthreads();
  for (int e = blockIdx.x * 256 + threadIdx.x; e < E; e += gridDim.x * 256)
    atomicAdd(&cnt[rows[e] >> RPB_SHIFT], 1);
  __syncthreads();
  for (int i = threadIdx.x; i < nbuck; i += 256)
    if (cnt[i]) atomicAdd(&bcnt[i], cnt[i]);
}

__global__ __launch_bounds__(1024)
void scan_buckets(const int* __restrict__ bcnt, int* __restrict__ bptr,
                  int* __restrict__ bcur, int nbuck, int E) {
  __shared__ int buf[1024];
  int t = threadIdx.x;
  int x = (t < nbuck) ? bcnt[t] : 0;
  buf[t] = x;
  __syncthreads();
#pragma unroll
  for (int off = 1; off < 1024; off <<= 1) {
    int v = (t >= off) ? buf[t - off] : 0;
    __syncthreads();
    buf[t] += v;
    __syncthreads();
  }
  if (t < nbuck) {
    int ex = buf[t] - x;
    bptr[t] = ex;
    bcur[t] = ex;
  }
  if (t == 0) bptr[nbuck] = E;
}

__global__ __launch_bounds__(256)
void bucket_scatter(const int* __restrict__ rows, const int* __restrict__ cols,
                    const float* __restrict__ vals, int* __restrict__ bcur,
                    int2* __restrict__ sorted, int E, int nbuck) {
  __shared__ int lcnt[MAXBUCK];
  __shared__ int lbase[MAXBUCK];
  const int t = threadIdx.x;
  const int e0 = blockIdx.x * CHUNK;
  const int e1 = min(e0 + CHUNK, E);

  for (int i = t; i < nbuck; i += 256) lcnt[i] = 0;
  __syncthreads();
  for (int e = e0 + t; e < e1; e += 256)
    atomicAdd(&lcnt[rows[e] >> RPB_SHIFT], 1);
  __syncthreads();
  for (int i = t; i < nbuck; i += 256) {
    int c = lcnt[i];
    lbase[i] = c ? atomicAdd(&bcur[i], c) : 0;
  }
  __syncthreads();
  for (int i = t; i < nbuck; i += 256) lcnt[i] = 0;
  __syncthreads();
  for (int e = e0 + t; e < e1; e += 256) {
    int r = rows[e];
    int b = r >> RPB_SHIFT;
    int lrow = r & (RPB - 1);
    int pos = lbase[b] + atomicAdd(&lcnt[b], 1);
    sorted[pos] = make_int2((lrow << COL_BITS) | cols[e], __float_as_int(vals[e]));
  }
}

__global__ __launch_bounds__(256)
void bucket_sort(int2* __restrict__ sorted, const int* __restrict__ bptr,
                 int* __restrict__ row_ptr, int* __restrict__ bflag,
                 int N, int E, int nbuck) {
  __shared__ int2 eds[SORT_CAP];   // 48 KB
  __shared__ int lcnt[RPB];
  __shared__ int loff[RPB];
  __shared__ int lcur[RPB];
  const int t = threadIdx.x;
  const int b = blockIdx.x;
  const int s = bptr[b];
  const int e = bptr[b + 1];
  const int cnt = e - s;
  const int row0 = b << RPB_SHIFT;

  if (b == 0 && t == 0) row_ptr[N] = E;

  if (cnt > SORT_CAP) {  // correctness fallback
    if (t == 0) bflag[b] = 1;
    if (t < RPB && row0 + t < N) row_ptr[row0 + t] = s;
    return;
  }
  if (t == 0) bflag[b] = 0;

  if (t < RPB) lcnt[t] = 0;
  __syncthreads();
  for (int j = s + t; j < e; j += 256) {
    int2 p = sorted[j];
    eds[j - s] = p;
    atomicAdd(&lcnt[p.x >> COL_BITS], 1);
  }
  __syncthreads();
  if (t < RPB) loff[t] = lcnt[t];
  __syncthreads();
  for (int off = 1; off < RPB; off <<= 1) {
    int v = (t < RPB && t >= off) ? loff[t - off] : 0;
    __syncthreads();
    if (t < RPB) loff[t] += v;
    __syncthreads();
  }
  if (t < RPB) {
    int ex = loff[t] - lcnt[t];
    loff[t] = ex;
    lcur[t] = 0;
    int grow = row0 + t;
    if (grow < N) row_ptr[grow] = s + ex;
  }
  __syncthreads();
  for (int idx = t; idx < cnt; idx += 256) {
    int2 p = eds[idx];
    int lr = p.x >> COL_BITS;
    int pos = s + loff[lr] + atomicAdd(&lcur[lr], 1);
    sorted[pos] = p;
  }
}

// ---------------- Reduce: one wave per output row (h is bf16) ----------------
__global__ __launch_bounds__(256)
void reduce_rows(const unsigned short* __restrict__ h, const int2* __restrict__ sorted,
                 const int* __restrict__ row_ptr, const int* __restrict__ bptr,
                 const int* __restrict__ bflag, float* __restrict__ out, int N) {
  int row = (blockIdx.x * 256 + threadIdx.x) >> 6;
  if (row >= N) return;
  int lane = threadIdx.x & 63;
  int sub = lane >> 4;
  int part = lane & 15;
  int b = row >> RPB_SHIFT;
  int lrow = row & (RPB - 1);
  bool filt = bflag[b] != 0;
  int s, e;
  if (!filt) {
    s = row_ptr[row];
    e = row_ptr[row + 1];
  } else {
    s = bptr[b];
    e = bptr[b + 1];
  }
  float4 acc = make_float4(0.f, 0.f, 0.f, 0.f);
  for (int j = s + sub; j < e; j += 4) {
    int2 p = sorted[j];
    if (filt && (p.x >> COL_BITS) != lrow) continue;
    float v = __int_as_float(p.y);
    int col = p.x & COL_MASK;
    uint2 hv = *reinterpret_cast<const uint2*>(&h[(size_t)col * MOUT + part * 4]);
    float h0 = __uint_as_float(hv.x << 16);
    float h1 = __uint_as_float(hv.x & 0xffff0000u);
    float h2 = __uint_as_float(hv.y << 16);
    float h3 = __uint_as_float(hv.y & 0xffff0000u);
    acc.x += v * h0;
    acc.y += v * h1;
    acc.z += v * h2;
    acc.w += v * h3;
  }
#pragma unroll
  for (int m = 16; m <= 32; m <<= 1) {
    acc.x += __shfl_xor(acc.x, m, 64);
    acc.y += __shfl_xor(acc.y, m, 64);
    acc.z += __shfl_xor(acc.z, m, 64);
    acc.w += __shfl_xor(acc.w, m, 64);
  }
  if (sub == 0)
    *reinterpret_cast<float4*>(&out[(size_t)row * MOUT + part * 4]) = acc;
}

// ---------------- Fallback: f32-atomic scatter (h bf16) ----------------
__global__ __launch_bounds__(256)
void scatter_edges(const unsigned short* __restrict__ h, const float* __restrict__ vals,
                   const int* __restrict__ rows, const int* __restrict__ cols,
                   float* __restrict__ out, int E) {
  long long idx = (long long)blockIdx.x * blockDim.x + threadIdx.x;
  int e = (int)(idx >> 4);
  int part = (int)(idx & 15);
  if (e >= E) return;
  int r = rows[e];
  int c = cols[e];
  float v = vals[e];
  uint2 hv = *reinterpret_cast<const uint2*>(&h[(size_t)c * MOUT + part * 4]);
  float* op = &out[(size_t)r * MOUT + part * 4];
  atomicAdd(op + 0, v * __uint_as_float(hv.x << 16));
  atomicAdd(op + 1, v * __uint_as_float(hv.x & 0xffff0000u));
  atomicAdd(op + 2, v * __uint_as_float(hv.y << 16));
  atomicAdd(op + 3, v * __uint_as_float(hv.y & 0xffff0000u));
}

static inline size_t align256(size_t x) { return (x + 255) & ~(size_t)255; }

extern "C" void kernel_launch(void* const* d_in, const int* in_sizes, int n_in,
                              void* d_out, int out_size, void* d_ws, size_t ws_size,
                              hipStream_t stream) {
  const float* x    = (const float*)d_in[0];
  const float* W    = (const float*)d_in[1];
  const float* bvec = (const float*)d_in[2];
  const float* vals = (const float*)d_in[3];
  const int* erows  = (const int*)d_in[4];
  const int* ecols  = (const int*)d_in[5];
  float* out = (float*)d_out;

  const int N = in_sizes[0] / KDIM;   // 100000
  const int E = in_sizes[3];          // 1600000
  const int nbuck = (N + RPB - 1) / RPB;  // 782

  // workspace layout
  char* ws = (char*)d_ws;
  size_t off_h  = 0;                                                    // h bf16 [N][64]
  size_t off_wt = align256(off_h + (size_t)N * MOUT * sizeof(short));   // wt bf16 [64][256]
  size_t off_bp = align256(off_wt + (size_t)MOUT * KDIM * sizeof(short));
  size_t off_bc = align256(off_bp + (size_t)(nbuck + 1) * sizeof(int));
  size_t off_cu = align256(off_bc + (size_t)nbuck * sizeof(int));
  size_t off_bf = align256(off_cu + (size_t)nbuck * sizeof(int));
  size_t off_rp = align256(off_bf + (size_t)nbuck * sizeof(int));
  size_t off_sp = align256(off_rp + (size_t)(N + 1) * sizeof(int));
  size_t need   = off_sp + (size_t)E * sizeof(int2);

  unsigned short* h  = (unsigned short*)(ws + off_h);
  unsigned short* wt = (unsigned short*)(ws + off_wt);

  dim3 blk256(256);
  wt_transpose<<<dim3(MOUT), blk256, 0, stream>>>(W, wt);
  gemm_mfma<<<dim3((N + 127) / 128), blk256, 0, stream>>>(x, wt, bvec, h, N);

  if (ws_size >= need && nbuck <= MAXBUCK && N < (1 << COL_BITS)) {
    int* bptr  = (int*)(ws + off_bp);
    int* bcnt  = (int*)(ws + off_bc);
    int* bcur  = (int*)(ws + off_cu);
    int* bflag = (int*)(ws + off_bf);
    int* row_ptr = (int*)(ws + off_rp);
    int2* sorted = (int2*)(ws + off_sp);

    hipMemsetAsync(bcnt, 0, (size_t)nbuck * sizeof(int), stream);
    bucket_hist<<<dim3(256), blk256, 0, stream>>>(erows, bcnt, E, nbuck);
    scan_buckets<<<dim3(1), dim3(1024), 0, stream>>>(bcnt, bptr, bcur, nbuck, E);
    bucket_scatter<<<dim3((E + CHUNK - 1) / CHUNK), blk256, 0, stream>>>(
        erows, ecols, vals, bcur, sorted, E, nbuck);
    bucket_sort<<<dim3(nbuck), blk256, 0, stream>>>(sorted, bptr, row_ptr, bflag, N, E, nbuck);
    reduce_rows<<<dim3(((size_t)N * 64 + 255) / 256), blk256, 0, stream>>>(
        h, sorted, row_ptr, bptr, bflag, out, N);
  } else {
    hipMemsetAsync(d_out, 0, (size_t)out_size * sizeof(float), stream);
    long long work = (long long)E * 16;
    scatter_edges<<<dim3((unsigned)((work + 255) / 256)), blk256, 0, stream>>>(h, vals, erows, ecols, out, E);
  }
}

// Round 6
// 144.525 us; speedup vs baseline: 5.4287x; 1.1207x over previous
//
#include <hip/hip_runtime.h>

// SIGN convolution: h = x @ W + b ; out = segment_sum(adj_vals[:,None] * h[edge_cols], edge_rows)
// Round 6: reduce_rows restructured for memory-level parallelism: 8 slots x 8 parts
// (uint4 gathers) + 2x manual unroll -> up to 16 edges (2KB) in flight per wave.
// r5 post-mortem: reduce was latency-bound (4 dependent 8B gathers/row, 1.4 TB/s).

#include <stdint.h>

constexpr int KDIM = 256;   // n_in
constexpr int MOUT = 64;    // n_out

constexpr int RPB = 128;        // rows per bucket
constexpr int RPB_SHIFT = 7;
constexpr int MAXBUCK = 1024;
constexpr int CHUNK = 8192;     // edges per scatter block
constexpr int COL_BITS = 20;
constexpr int COL_MASK = (1 << COL_BITS) - 1;
constexpr int SORT_CAP = 6144;  // 48KB LDS stage; mean bucket = 2046 here

typedef __attribute__((ext_vector_type(8))) short short8v;
typedef __attribute__((ext_vector_type(4))) float f32x4;

__device__ __forceinline__ unsigned short f2bf(float f) {
  unsigned u = __float_as_uint(f);
  return (unsigned short)((u + 0x7fffu + ((u >> 16) & 1u)) >> 16);
}

// ---------------- W transpose + bf16 convert (one-time, 32KB) ----------------
__global__ __launch_bounds__(256)
void wt_transpose(const float* __restrict__ W, unsigned short* __restrict__ wt) {
  int n = blockIdx.x;
  int k = threadIdx.x;
  wt[n * KDIM + k] = f2bf(W[(size_t)k * MOUT + n]);
}

// ---------------- Phase 1: h = bf16(x @ W + b) via MFMA ----------------
__global__ __launch_bounds__(256)
void gemm_mfma(const float* __restrict__ x, const unsigned short* __restrict__ wt,
               const float* __restrict__ bvec, unsigned short* __restrict__ h, int N) {
  __shared__ unsigned short wlds[MOUT][264];  // 528B rows: 2-way bank aliasing only

  const int t = threadIdx.x;
  for (int i = t; i < MOUT * 32; i += 256) {
    int n = i >> 5, seg = i & 31;
    uint4 v = *reinterpret_cast<const uint4*>(&wt[n * KDIM + seg * 8]);
    *reinterpret_cast<uint4*>(&wlds[n][seg * 8]) = v;
  }
  __syncthreads();

  const int wave = t >> 6, lane = t & 63;
  const int lo = lane & 15, hi = lane >> 4;
  const int rowbase = blockIdx.x * 128 + wave * 32;

  float bias[4];
#pragma unroll
  for (int nt = 0; nt < 4; ++nt) bias[nt] = bvec[nt * 16 + lo];

  f32x4 acc[2][4] = {};

#pragma unroll
  for (int ks = 0; ks < 8; ++ks) {
    short8v bfr[4];
#pragma unroll
    for (int nt = 0; nt < 4; ++nt)
      bfr[nt] = *reinterpret_cast<const short8v*>(&wlds[nt * 16 + lo][ks * 32 + hi * 8]);
#pragma unroll
    for (int mr = 0; mr < 2; ++mr) {
      int r = rowbase + mr * 16 + lo;
      if (r >= N) r = N - 1;  // clamp; stores guarded
      const float* xp = &x[(size_t)r * KDIM + ks * 32 + hi * 8];
      float4 p0 = *reinterpret_cast<const float4*>(xp);
      float4 p1 = *reinterpret_cast<const float4*>(xp + 4);
      short8v a;
      a[0] = (short)f2bf(p0.x); a[1] = (short)f2bf(p0.y);
      a[2] = (short)f2bf(p0.z); a[3] = (short)f2bf(p0.w);
      a[4] = (short)f2bf(p1.x); a[5] = (short)f2bf(p1.y);
      a[6] = (short)f2bf(p1.z); a[7] = (short)f2bf(p1.w);
#pragma unroll
      for (int nt = 0; nt < 4; ++nt)
        acc[mr][nt] = __builtin_amdgcn_mfma_f32_16x16x32_bf16(a, bfr[nt], acc[mr][nt], 0, 0, 0);
    }
  }

#pragma unroll
  for (int mr = 0; mr < 2; ++mr)
#pragma unroll
    for (int reg = 0; reg < 4; ++reg) {
      int row = rowbase + mr * 16 + hi * 4 + reg;
      if (row < N) {
#pragma unroll
        for (int nt = 0; nt < 4; ++nt)
          h[(size_t)row * MOUT + nt * 16 + lo] = f2bf(acc[mr][nt][reg] + bias[nt]);
      }
    }
}

// ---------------- Bucket CSR build (unchanged) ----------------
__global__ __launch_bounds__(256)
void bucket_hist(const int* __restrict__ rows, int* __restrict__ bcnt, int E, int nbuck) {
  __shared__ int cnt[MAXBUCK];
  for (int i = threadIdx.x; i < nbuck; i += 256) cnt[i] = 0;
  __syncthreads();
  for (int e = blockIdx.x * 256 + threadIdx.x; e < E; e += gridDim.x * 256)
    atomicAdd(&cnt[rows[e] >> RPB_SHIFT], 1);
  __syncthreads();
  for (int i = threadIdx.x; i < nbuck; i += 256)
    if (cnt[i]) atomicAdd(&bcnt[i], cnt[i]);
}

__global__ __launch_bounds__(1024)
void scan_buckets(const int* __restrict__ bcnt, int* __restrict__ bptr,
                  int* __restrict__ bcur, int nbuck, int E) {
  __shared__ int buf[1024];
  int t = threadIdx.x;
  int x = (t < nbuck) ? bcnt[t] : 0;
  buf[t] = x;
  __syncthreads();
#pragma unroll
  for (int off = 1; off < 1024; off <<= 1) {
    int v = (t >= off) ? buf[t - off] : 0;
    __syncthreads();
    buf[t] += v;
    __syncthreads();
  }
  if (t < nbuck) {
    int ex = buf[t] - x;
    bptr[t] = ex;
    bcur[t] = ex;
  }
  if (t == 0) bptr[nbuck] = E;
}

__global__ __launch_bounds__(256)
void bucket_scatter(const int* __restrict__ rows, const int* __restrict__ cols,
                    const float* __restrict__ vals, int* __restrict__ bcur,
                    int2* __restrict__ sorted, int E, int nbuck) {
  __shared__ int lcnt[MAXBUCK];
  __shared__ int lbase[MAXBUCK];
  const int t = threadIdx.x;
  const int e0 = blockIdx.x * CHUNK;
  const int e1 = min(e0 + CHUNK, E);

  for (int i = t; i < nbuck; i += 256) lcnt[i] = 0;
  __syncthreads();
  for (int e = e0 + t; e < e1; e += 256)
    atomicAdd(&lcnt[rows[e] >> RPB_SHIFT], 1);
  __syncthreads();
  for (int i = t; i < nbuck; i += 256) {
    int c = lcnt[i];
    lbase[i] = c ? atomicAdd(&bcur[i], c) : 0;
  }
  __syncthreads();
  for (int i = t; i < nbuck; i += 256) lcnt[i] = 0;
  __syncthreads();
  for (int e = e0 + t; e < e1; e += 256) {
    int r = rows[e];
    int b = r >> RPB_SHIFT;
    int lrow = r & (RPB - 1);
    int pos = lbase[b] + atomicAdd(&lcnt[b], 1);
    sorted[pos] = make_int2((lrow << COL_BITS) | cols[e], __float_as_int(vals[e]));
  }
}

__global__ __launch_bounds__(256)
void bucket_sort(int2* __restrict__ sorted, const int* __restrict__ bptr,
                 int* __restrict__ row_ptr, int* __restrict__ bflag,
                 int N, int E, int nbuck) {
  __shared__ int2 eds[SORT_CAP];   // 48 KB
  __shared__ int lcnt[RPB];
  __shared__ int loff[RPB];
  __shared__ int lcur[RPB];
  const int t = threadIdx.x;
  const int b = blockIdx.x;
  const int s = bptr[b];
  const int e = bptr[b + 1];
  const int cnt = e - s;
  const int row0 = b << RPB_SHIFT;

  if (b == 0 && t == 0) row_ptr[N] = E;

  if (cnt > SORT_CAP) {  // correctness fallback
    if (t == 0) bflag[b] = 1;
    if (t < RPB && row0 + t < N) row_ptr[row0 + t] = s;
    return;
  }
  if (t == 0) bflag[b] = 0;

  if (t < RPB) lcnt[t] = 0;
  __syncthreads();
  for (int j = s + t; j < e; j += 256) {
    int2 p = sorted[j];
    eds[j - s] = p;
    atomicAdd(&lcnt[p.x >> COL_BITS], 1);
  }
  __syncthreads();
  if (t < RPB) loff[t] = lcnt[t];
  __syncthreads();
  for (int off = 1; off < RPB; off <<= 1) {
    int v = (t < RPB && t >= off) ? loff[t - off] : 0;
    __syncthreads();
    if (t < RPB) loff[t] += v;
    __syncthreads();
  }
  if (t < RPB) {
    int ex = loff[t] - lcnt[t];
    loff[t] = ex;
    lcur[t] = 0;
    int grow = row0 + t;
    if (grow < N) row_ptr[grow] = s + ex;
  }
  __syncthreads();
  for (int idx = t; idx < cnt; idx += 256) {
    int2 p = eds[idx];
    int lr = p.x >> COL_BITS;
    int pos = s + loff[lr] + atomicAdd(&lcur[lr], 1);
    sorted[pos] = p;
  }
}

// ---------------- Reduce: one wave per row, 8 slots x 8 parts, 2x unroll ----------------
__device__ __forceinline__ void edge_fma(float* acc, const unsigned short* h,
                                         int2 p, int part) {
  float v = __int_as_float(p.y);
  int col = p.x & COL_MASK;
  uint4 hv = *reinterpret_cast<const uint4*>(&h[(size_t)col * MOUT + part * 8]);
  acc[0] += v * __uint_as_float(hv.x << 16);
  acc[1] += v * __uint_as_float(hv.x & 0xffff0000u);
  acc[2] += v * __uint_as_float(hv.y << 16);
  acc[3] += v * __uint_as_float(hv.y & 0xffff0000u);
  acc[4] += v * __uint_as_float(hv.z << 16);
  acc[5] += v * __uint_as_float(hv.z & 0xffff0000u);
  acc[6] += v * __uint_as_float(hv.w << 16);
  acc[7] += v * __uint_as_float(hv.w & 0xffff0000u);
}

__global__ __launch_bounds__(256)
void reduce_rows(const unsigned short* __restrict__ h, const int2* __restrict__ sorted,
                 const int* __restrict__ row_ptr, const int* __restrict__ bptr,
                 const int* __restrict__ bflag, float* __restrict__ out, int N) {
  int row = (blockIdx.x * 256 + threadIdx.x) >> 6;
  if (row >= N) return;
  int lane = threadIdx.x & 63;
  int slot = lane >> 3;   // 8 edge slots
  int part = lane & 7;    // 16B (8 bf16) of the 128B h row
  int b = row >> RPB_SHIFT;
  int lrow = row & (RPB - 1);
  bool filt = bflag[b] != 0;

  float acc[8];
#pragma unroll
  for (int i = 0; i < 8; ++i) acc[i] = 0.f;

  if (!filt) {
    int s = row_ptr[row];
    int e = row_ptr[row + 1];
    int j = s + slot;
    // 2x unrolled hot loop: both sorted reads then both gathers issued up front
    for (; j + 8 < e; j += 16) {
      int2 p0 = sorted[j];
      int2 p1 = sorted[j + 8];
      float v0 = __int_as_float(p0.y);
      float v1 = __int_as_float(p1.y);
      const uint4* a0 = reinterpret_cast<const uint4*>(
          &h[(size_t)(p0.x & COL_MASK) * MOUT + part * 8]);
      const uint4* a1 = reinterpret_cast<const uint4*>(
          &h[(size_t)(p1.x & COL_MASK) * MOUT + part * 8]);
      uint4 h0 = *a0;
      uint4 h1 = *a1;
      acc[0] += v0 * __uint_as_float(h0.x << 16);
      acc[1] += v0 * __uint_as_float(h0.x & 0xffff0000u);
      acc[2] += v0 * __uint_as_float(h0.y << 16);
      acc[3] += v0 * __uint_as_float(h0.y & 0xffff0000u);
      acc[4] += v0 * __uint_as_float(h0.z << 16);
      acc[5] += v0 * __uint_as_float(h0.z & 0xffff0000u);
      acc[6] += v0 * __uint_as_float(h0.w << 16);
      acc[7] += v0 * __uint_as_float(h0.w & 0xffff0000u);
      acc[0] += v1 * __uint_as_float(h1.x << 16);
      acc[1] += v1 * __uint_as_float(h1.x & 0xffff0000u);
      acc[2] += v1 * __uint_as_float(h1.y << 16);
      acc[3] += v1 * __uint_as_float(h1.y & 0xffff0000u);
      acc[4] += v1 * __uint_as_float(h1.z << 16);
      acc[5] += v1 * __uint_as_float(h1.z & 0xffff0000u);
      acc[6] += v1 * __uint_as_float(h1.w << 16);
      acc[7] += v1 * __uint_as_float(h1.w & 0xffff0000u);
    }
    if (j < e) edge_fma(acc, h, sorted[j], part);
  } else {
    // cold correctness fallback: filter-scan the whole bucket
    int s = bptr[b];
    int e = bptr[b + 1];
    for (int j = s + slot; j < e; j += 8) {
      int2 p = sorted[j];
      if ((p.x >> COL_BITS) != lrow) continue;
      edge_fma(acc, h, p, part);
    }
  }

#pragma unroll
  for (int m = 8; m <= 32; m <<= 1)
#pragma unroll
    for (int i = 0; i < 8; ++i)
      acc[i] += __shfl_xor(acc[i], m, 64);

  if (slot == 0) {
    float* op = &out[(size_t)row * MOUT + part * 8];
    *reinterpret_cast<float4*>(op)     = make_float4(acc[0], acc[1], acc[2], acc[3]);
    *reinterpret_cast<float4*>(op + 4) = make_float4(acc[4], acc[5], acc[6], acc[7]);
  }
}

// ---------------- Fallback: f32-atomic scatter (h bf16) ----------------
__global__ __launch_bounds__(256)
void scatter_edges(const unsigned short* __restrict__ h, const float* __restrict__ vals,
                   const int* __restrict__ rows, const int* __restrict__ cols,
                   float* __restrict__ out, int E) {
  long long idx = (long long)blockIdx.x * blockDim.x + threadIdx.x;
  int e = (int)(idx >> 4);
  int part = (int)(idx & 15);
  if (e >= E) return;
  int r = rows[e];
  int c = cols[e];
  float v = vals[e];
  uint2 hv = *reinterpret_cast<const uint2*>(&h[(size_t)c * MOUT + part * 4]);
  float* op = &out[(size_t)r * MOUT + part * 4];
  atomicAdd(op + 0, v * __uint_as_float(hv.x << 16));
  atomicAdd(op + 1, v * __uint_as_float(hv.x & 0xffff0000u));
  atomicAdd(op + 2, v * __uint_as_float(hv.y << 16));
  atomicAdd(op + 3, v * __uint_as_float(hv.y & 0xffff0000u));
}

static inline size_t align256(size_t x) { return (x + 255) & ~(size_t)255; }

extern "C" void kernel_launch(void* const* d_in, const int* in_sizes, int n_in,
                              void* d_out, int out_size, void* d_ws, size_t ws_size,
                              hipStream_t stream) {
  const float* x    = (const float*)d_in[0];
  const float* W    = (const float*)d_in[1];
  const float* bvec = (const float*)d_in[2];
  const float* vals = (const float*)d_in[3];
  const int* erows  = (const int*)d_in[4];
  const int* ecols  = (const int*)d_in[5];
  float* out = (float*)d_out;

  const int N = in_sizes[0] / KDIM;   // 100000
  const int E = in_sizes[3];          // 1600000
  const int nbuck = (N + RPB - 1) / RPB;  // 782

  // workspace layout
  char* ws = (char*)d_ws;
  size_t off_h  = 0;                                                    // h bf16 [N][64]
  size_t off_wt = align256(off_h + (size_t)N * MOUT * sizeof(short));   // wt bf16 [64][256]
  size_t off_bp = align256(off_wt + (size_t)MOUT * KDIM * sizeof(short));
  size_t off_bc = align256(off_bp + (size_t)(nbuck + 1) * sizeof(int));
  size_t off_cu = align256(off_bc + (size_t)nbuck * sizeof(int));
  size_t off_bf = align256(off_cu + (size_t)nbuck * sizeof(int));
  size_t off_rp = align256(off_bf + (size_t)nbuck * sizeof(int));
  size_t off_sp = align256(off_rp + (size_t)(N + 1) * sizeof(int));
  size_t need   = off_sp + (size_t)E * sizeof(int2);

  unsigned short* h  = (unsigned short*)(ws + off_h);
  unsigned short* wt = (unsigned short*)(ws + off_wt);

  dim3 blk256(256);
  wt_transpose<<<dim3(MOUT), blk256, 0, stream>>>(W, wt);
  gemm_mfma<<<dim3((N + 127) / 128), blk256, 0, stream>>>(x, wt, bvec, h, N);

  if (ws_size >= need && nbuck <= MAXBUCK && N < (1 << COL_BITS)) {
    int* bptr  = (int*)(ws + off_bp);
    int* bcnt  = (int*)(ws + off_bc);
    int* bcur  = (int*)(ws + off_cu);
    int* bflag = (int*)(ws + off_bf);
    int* row_ptr = (int*)(ws + off_rp);
    int2* sorted = (int2*)(ws + off_sp);

    hipMemsetAsync(bcnt, 0, (size_t)nbuck * sizeof(int), stream);
    bucket_hist<<<dim3(256), blk256, 0, stream>>>(erows, bcnt, E, nbuck);
    scan_buckets<<<dim3(1), dim3(1024), 0, stream>>>(bcnt, bptr, bcur, nbuck, E);
    bucket_scatter<<<dim3((E + CHUNK - 1) / CHUNK), blk256, 0, stream>>>(
        erows, ecols, vals, bcur, sorted, E, nbuck);
    bucket_sort<<<dim3(nbuck), blk256, 0, stream>>>(sorted, bptr, row_ptr, bflag, N, E, nbuck);
    reduce_rows<<<dim3(((size_t)N * 64 + 255) / 256), blk256, 0, stream>>>(
        h, sorted, row_ptr, bptr, bflag, out, N);
  } else {
    hipMemsetAsync(d_out, 0, (size_t)out_size * sizeof(float), stream);
    long long work = (long long)E * 16;
    scatter_edges<<<dim3((unsigned)((work + 255) / 256)), blk256, 0, stream>>>(h, vals, erows, ecols, out, E);
  }
}